// Round 12
// baseline (192.182 us; speedup 1.0000x reference)
//
#include <hip/hip_runtime.h>
#include <hip/hip_fp16.h>

#define DIM 64
#define BN_EPS 1e-5f
#define RSHIFT 8          // 256 nodes per range
#define RSIZE 256
#define EPB 8192          // edges per bin block
#define ABLK 2048         // aggregation blocks
#define PSLOT 16          // pstats2 accumulation slots
#define BH 512            // bhist row stride (bins per block record)

// ---------------- binhist: per-(block,bin) edge counts, no global atomics ----------------
__global__ __launch_bounds__(256) void k_binhist(const int* __restrict__ dst,
                                                 int* __restrict__ bhist,
                                                 int* __restrict__ donecnt,
                                                 int P, int E) {
    if (blockIdx.x == 0 && threadIdx.x == 0) *donecnt = 0;
    __shared__ int hist[BH];
    for (int b0 = threadIdx.x; b0 < BH; b0 += 256) hist[b0] = 0;
    __syncthreads();
    const int base4 = blockIdx.x * (EPB / 4);
    for (int i = 0; i < EPB / 4 / 256; ++i) {
        int idx = base4 + i * 256 + threadIdx.x;
        int e0 = idx << 2;
        if (e0 + 3 < E) {
            int4 d4 = ((const int4*)dst)[idx];
            atomicAdd(&hist[d4.x >> RSHIFT], 1);
            atomicAdd(&hist[d4.y >> RSHIFT], 1);
            atomicAdd(&hist[d4.z >> RSHIFT], 1);
            atomicAdd(&hist[d4.w >> RSHIFT], 1);
        } else {
            for (int k = 0; k < 4; ++k)
                if (e0 + k < E) atomicAdd(&hist[dst[e0 + k] >> RSHIFT], 1);
        }
    }
    __syncthreads();
    for (int b0 = threadIdx.x; b0 < P; b0 += 256)
        bhist[blockIdx.x * BH + b0] = hist[b0];
}

// ---------------- binscan: per-bin scan over blocks; LAST block also does the global scan ----------------
// After: bhist[blk*BH+r] = exclusive prefix of bin r over blocks 0..blk-1; gbase = bin starts.
__global__ __launch_bounds__(128) void k_binscan(int* __restrict__ bhist,
                                                 int* __restrict__ bintot,
                                                 int* __restrict__ gbase,
                                                 int* __restrict__ rowptr,
                                                 int* __restrict__ donecnt,
                                                 int P, int N, int E, int nbin) {
    __shared__ int s[128];
    __shared__ int lastflag;
    const int r = blockIdx.x;
    int carry = 0;
    for (int base = 0; base < nbin; base += 128) {
        const int idx = base + threadIdx.x;
        int v = (idx < nbin) ? bhist[idx * BH + r] : 0;
        s[threadIdx.x] = v;
        __syncthreads();
        for (int off = 1; off < 128; off <<= 1) {
            int t = (threadIdx.x >= (unsigned)off) ? s[threadIdx.x - off] : 0;
            __syncthreads();
            s[threadIdx.x] += t;
            __syncthreads();
        }
        if (idx < nbin) bhist[idx * BH + r] = carry + s[threadIdx.x] - v;
        carry += s[127];
        __syncthreads();
    }
    if (threadIdx.x == 0) {
        bintot[r] = carry;
        __threadfence();                       // device-scope release of bintot[r]
        int prev = atomicAdd(donecnt, 1);
        lastflag = (prev == (int)gridDim.x - 1);
    }
    __syncthreads();
    if (!lastflag) return;
    // last block: exclusive scan of bintot[0..P) -> gbase (atomic loads for cross-XCD visibility)
    int carry2 = 0;
    for (int base = 0; base < P; base += 128) {
        const int idx = base + threadIdx.x;
        int v = (idx < P) ? atomicAdd(&bintot[idx], 0) : 0;
        s[threadIdx.x] = v;
        __syncthreads();
        for (int off = 1; off < 128; off <<= 1) {
            int t = (threadIdx.x >= (unsigned)off) ? s[threadIdx.x - off] : 0;
            __syncthreads();
            s[threadIdx.x] += t;
            __syncthreads();
        }
        if (idx < P) gbase[idx] = carry2 + s[threadIdx.x] - v;
        carry2 += s[127];
        __syncthreads();
    }
    if (threadIdx.x == 0) {
        gbase[P] = carry2;   // = E
        rowptr[N] = E;
    }
}

// ---------------- bin (single pass): group edges by dst-range into block-exclusive runs ----------------
// pk[pos] = (dstlocal << 20) | src   (src < 2^20, dstlocal < 256)
__global__ __launch_bounds__(256) void k_bin(const int* __restrict__ src,
                                             const int* __restrict__ dst,
                                             const int* __restrict__ gbase,
                                             const int* __restrict__ bhist,
                                             int* __restrict__ pk, int P, int E) {
    __shared__ int gofs[BH], lcnt[BH];
    for (int b0 = threadIdx.x; b0 < P; b0 += 256) {
        gofs[b0] = gbase[b0] + bhist[blockIdx.x * BH + b0];
        lcnt[b0] = 0;
    }
    __syncthreads();
    const int base4 = blockIdx.x * (EPB / 4);
    for (int i = 0; i < EPB / 4 / 256; ++i) {
        int idx = base4 + i * 256 + threadIdx.x;
        int e0 = idx << 2;
        if (e0 + 3 < E) {
            int4 d4 = ((const int4*)dst)[idx];
            int4 s4 = ((const int4*)src)[idx];
            int b0;
            b0 = d4.x >> RSHIFT; pk[gofs[b0] + atomicAdd(&lcnt[b0], 1)] = ((d4.x & (RSIZE - 1)) << 20) | s4.x;
            b0 = d4.y >> RSHIFT; pk[gofs[b0] + atomicAdd(&lcnt[b0], 1)] = ((d4.y & (RSIZE - 1)) << 20) | s4.y;
            b0 = d4.z >> RSHIFT; pk[gofs[b0] + atomicAdd(&lcnt[b0], 1)] = ((d4.z & (RSIZE - 1)) << 20) | s4.z;
            b0 = d4.w >> RSHIFT; pk[gofs[b0] + atomicAdd(&lcnt[b0], 1)] = ((d4.w & (RSIZE - 1)) << 20) | s4.w;
        } else {
            for (int k = 0; k < 4; ++k) {
                if (e0 + k < E) {
                    int d = dst[e0 + k];
                    int b0 = d >> RSHIFT;
                    pk[gofs[b0] + atomicAdd(&lcnt[b0], 1)] = ((d & (RSIZE - 1)) << 20) | src[e0 + k];
                }
            }
        }
    }
}

// ---------------- sortrange: per-range LDS counting sort; derives deg/dinv/rowptr ----------------
__global__ __launch_bounds__(256) void k_sortrange(
        const int* __restrict__ gbase, const int* __restrict__ pk,
        int* __restrict__ ssrc, int* __restrict__ rowptr,
        float* __restrict__ dinv, int N) {
    __shared__ int lhist[256], ls[256], lcur[256];
    const int r = blockIdx.x;
    const int d0 = r << RSHIFT;
    const int i = d0 + threadIdx.x;
    const int ebeg = gbase[r], eend = gbase[r + 1];
    lhist[threadIdx.x] = 0;
    __syncthreads();
    for (int j = ebeg + threadIdx.x; j < eend; j += 256)
        atomicAdd(&lhist[((unsigned)pk[j]) >> 20], 1);
    __syncthreads();
    int dg = lhist[threadIdx.x];
    if (i < N) dinv[i] = rsqrtf((float)dg + 1.0f);  // +1 self-loop
    ls[threadIdx.x] = dg;
    __syncthreads();
    for (int off = 1; off < 256; off <<= 1) {
        int t = (threadIdx.x >= (unsigned)off) ? ls[threadIdx.x - off] : 0;
        __syncthreads();
        ls[threadIdx.x] += t;
        __syncthreads();
    }
    int lofs = ls[threadIdx.x] - dg;  // local exclusive
    lcur[threadIdx.x] = ebeg + lofs;  // absolute cursor
    if (i < N) rowptr[i] = ebeg + lofs;
    __syncthreads();
    for (int j = ebeg + threadIdx.x; j < eend; j += 256) {
        int p = pk[j];
        ssrc[atomicAdd(&lcur[((unsigned)p) >> 20], 1)] = p & 0xFFFFF;
    }
}

// ---------------- gemm: 4 threads/row, 16 outputs each; emits h2 = fp16(h*dinv); zeroes pstats2 ----------------
__global__ __launch_bounds__(256) void k_gemm(const float* __restrict__ x,
                                              const float* __restrict__ W,
                                              const float* __restrict__ dinv,
                                              __half* __restrict__ h2,
                                              float* __restrict__ pstats2, int N) {
    if (blockIdx.x == 0) {
        for (int i = threadIdx.x; i < PSLOT * 128; i += 256) pstats2[i] = 0.f;
    }
    __shared__ float Wl[DIM * DIM];
    for (int i = threadIdx.x; i < DIM * DIM; i += 256) Wl[i] = W[i];
    __syncthreads();
    int t = blockIdx.x * 256 + threadIdx.x;
    int r = t >> 2;       // row
    int q = t & 3;        // output-feature quarter
    if (r >= N) return;
    const float4* xr4 = (const float4*)(x + (size_t)r * DIM);
    float4 acc[4];
#pragma unroll
    for (int j = 0; j < 4; ++j) acc[j] = make_float4(0.f, 0.f, 0.f, 0.f);
    for (int k0 = 0; k0 < 16; ++k0) {
        float4 xv = xr4[k0];
#pragma unroll
        for (int kk = 0; kk < 4; ++kk) {
            float xs = (&xv.x)[kk];
            const float4* wrow = (const float4*)(Wl + (k0 * 4 + kk) * DIM) + (q << 2);
#pragma unroll
            for (int j = 0; j < 4; ++j) {
                float4 w = wrow[j];
                acc[j].x += xs * w.x;
                acc[j].y += xs * w.y;
                acc[j].z += xs * w.z;
                acc[j].w += xs * w.w;
            }
        }
    }
    float dr = dinv[r];
    float4* hr4 = (float4*)(h2 + (size_t)r * DIM) + (q << 1);
    union { __half2 h[4]; float4 f4; } pack;
#pragma unroll
    for (int j = 0; j < 4; j += 2) {
        pack.h[0] = __float22half2_rn(make_float2(acc[j].x * dr, acc[j].y * dr));
        pack.h[1] = __float22half2_rn(make_float2(acc[j].z * dr, acc[j].w * dr));
        pack.h[2] = __float22half2_rn(make_float2(acc[j + 1].x * dr, acc[j + 1].y * dr));
        pack.h[3] = __float22half2_rn(make_float2(acc[j + 1].z * dr, acc[j + 1].w * dr));
        hr4[j >> 1] = pack.f4;
    }
}

// ---------------- nodeagg: node-PAIR pull (wave=2 nodes, lane=feature), NO output atomics ----------------
// Writes a = relu((self+sum)*dinv+b) as fp16; atomically folds BN partials into pstats2 slots.
__global__ __launch_bounds__(256) void k_nodeagg(
        const int* __restrict__ rowptr, const int* __restrict__ ssrc,
        const __half* __restrict__ h2, const float* __restrict__ dinv,
        const float* __restrict__ b, __half* __restrict__ a2,
        float* __restrict__ pstats2, int N) {
    const int lane = threadIdx.x & 63;
    const int w = threadIdx.x >> 6;
    const float bl = b[lane];
    const __half* hb = h2 + lane;
    float psum = 0.f, psq = 0.f;
    const int npairs = N >> 1;  // N even (100000)
    for (int t = blockIdx.x * 4 + w; t < npairs; t += ABLK * 4) {
        const int i0 = t << 1;
        const int rb0 = rowptr[i0], rb1 = rowptr[i0 + 1], rb2 = rowptr[i0 + 2];
        float acc0 = __half2float(hb[(size_t)i0 * DIM]);        // self term node0
        float acc1 = __half2float(hb[(size_t)(i0 + 1) * DIM]);  // self term node1
        const int total = rb2 - rb0;
        for (int j0 = 0; j0 < total; j0 += 64) {
            const int m = min(64, total - j0);
            const int c = rb1 - rb0 - j0;   // local boundary (wave-uniform)
            int sv = ssrc[rb0 + j0 + min(lane, m - 1)];
            int j = 0;
            for (; j + 16 <= m; j += 16) {
                int sA[16];
                float vA[16];
#pragma unroll
                for (int k = 0; k < 16; ++k) sA[k] = __builtin_amdgcn_readlane(sv, j + k);
#pragma unroll
                for (int k = 0; k < 16; ++k) vA[k] = __half2float(hb[(size_t)sA[k] * DIM]);
#pragma unroll
                for (int k = 0; k < 16; ++k) {
                    if (j + k < c) acc0 += vA[k]; else acc1 += vA[k];
                }
            }
            if (j < m) {
                const int r = m - j;        // 1..15, wave-uniform
                int sA[16];
                float vA[16];
#pragma unroll
                for (int k = 0; k < 16; ++k) sA[k] = __builtin_amdgcn_readlane(sv, j + min(k, r - 1));
#pragma unroll
                for (int k = 0; k < 16; ++k) vA[k] = __half2float(hb[(size_t)sA[k] * DIM]);
#pragma unroll
                for (int k = 0; k < 16; ++k) {
                    if (k < r) { if (j + k < c) acc0 += vA[k]; else acc1 += vA[k]; }
                }
            }
        }
        float a0 = fmaxf(acc0 * dinv[i0] + bl, 0.f);
        float a1 = fmaxf(acc1 * dinv[i0 + 1] + bl, 0.f);
        a2[(size_t)i0 * DIM + lane] = __float2half_rn(a0);
        a2[(size_t)(i0 + 1) * DIM + lane] = __float2half_rn(a1);
        psum += a0 + a1;
        psq += a0 * a0 + a1 * a1;
    }
    __shared__ float s1[256], s2[256];
    s1[threadIdx.x] = psum;
    s2[threadIdx.x] = psq;
    __syncthreads();
    if (threadIdx.x < 128) {
        s1[threadIdx.x] += s1[threadIdx.x + 128];
        s2[threadIdx.x] += s2[threadIdx.x + 128];
    }
    __syncthreads();
    if (threadIdx.x < 64) {
        const int slot = (blockIdx.x & (PSLOT - 1)) * 128;
        atomicAdd(&pstats2[slot + threadIdx.x], s1[threadIdx.x] + s1[threadIdx.x + 64]);
        atomicAdd(&pstats2[slot + 64 + threadIdx.x], s2[threadIdx.x] + s2[threadIdx.x + 64]);
    }
}

// ---------------- bn2: inline finstats (per-block, L2-hot) + out = a2*scale + shift ----------------
__global__ __launch_bounds__(256) void k_bn2(const __half* __restrict__ a2,
                                             const float* __restrict__ pstats2,
                                             const float* __restrict__ gamma,
                                             const float* __restrict__ beta,
                                             float* __restrict__ out, int total8, int N) {
    __shared__ float ssc[64], ssh[64];
    if (threadIdx.x < 128) {
        float s = 0.f;
#pragma unroll
        for (int k = 0; k < PSLOT; ++k) s += pstats2[k * 128 + threadIdx.x];
        if (threadIdx.x < 64) ssc[threadIdx.x] = s;       // feature sums
        else ssh[threadIdx.x - 64] = s;                    // feature sumsq
    }
    __syncthreads();
    if (threadIdx.x < 64) {
        float inv_n = 1.0f / (float)N;
        float mean = ssc[threadIdx.x] * inv_n;
        float var = ssh[threadIdx.x] * inv_n - mean * mean;
        float istd = rsqrtf(var + BN_EPS);
        float sc = gamma[threadIdx.x] * istd;
        ssc[threadIdx.x] = sc;
        ssh[threadIdx.x] = beta[threadIdx.x] - mean * sc;
    }
    __syncthreads();
    int i = blockIdx.x * blockDim.x + threadIdx.x;
    const int stride = gridDim.x * blockDim.x;  // 262144 ≡ 0 (mod 8)
    const int f8 = i & 7;
    const float4 sc0 = ((const float4*)ssc)[f8 * 2];
    const float4 sc1 = ((const float4*)ssc)[f8 * 2 + 1];
    const float4 sh0 = ((const float4*)ssh)[f8 * 2];
    const float4 sh1 = ((const float4*)ssh)[f8 * 2 + 1];
    for (; i < total8; i += stride) {
        union { float4 f; __half2 h[4]; } u;
        u.f = ((const float4*)a2)[i];
        float2 p0 = __half22float2(u.h[0]);
        float2 p1 = __half22float2(u.h[1]);
        float2 p2 = __half22float2(u.h[2]);
        float2 p3 = __half22float2(u.h[3]);
        float4 o0 = make_float4(p0.x * sc0.x + sh0.x, p0.y * sc0.y + sh0.y,
                                p1.x * sc0.z + sh0.z, p1.y * sc0.w + sh0.w);
        float4 o1 = make_float4(p2.x * sc1.x + sh1.x, p2.y * sc1.y + sh1.y,
                                p3.x * sc1.z + sh1.z, p3.y * sc1.w + sh1.w);
        ((float4*)out)[(size_t)i * 2] = o0;
        ((float4*)out)[(size_t)i * 2 + 1] = o1;
    }
}

extern "C" void kernel_launch(void* const* d_in, const int* in_sizes, int n_in,
                              void* d_out, int out_size, void* d_ws, size_t ws_size,
                              hipStream_t stream) {
    const float* x     = (const float*)d_in[0];
    const int*   ei    = (const int*)d_in[1];
    const float* W     = (const float*)d_in[2];
    const float* b     = (const float*)d_in[3];
    const float* gamma = (const float*)d_in[4];
    const float* beta  = (const float*)d_in[5];
    float* out = (float*)d_out;

    const int N = in_sizes[0] / DIM;  // 100000
    const int E = in_sizes[1] / 2;    // 1000000
    const int* esrc = ei;
    const int* edst = ei + E;
    const int P = (N + RSIZE - 1) >> RSHIFT;   // 391 ranges (<= 512)
    const int nbin = (E + EPB - 1) / EPB;      // 123 bin blocks

    // workspace layout
    char* ws = (char*)d_ws;
    size_t off = 0;
    int* bhist = (int*)(ws + off);      off += (size_t)nbin * BH * sizeof(int);
    off = (off + 255) & ~(size_t)255;
    int* bintot = (int*)(ws + off);     off += 512 * sizeof(int);
    int* gbase = (int*)(ws + off);      off += 520 * sizeof(int);
    off = (off + 255) & ~(size_t)255;
    int* donecnt = (int*)(ws + off);    off += 256;  // isolated line
    off = (off + 255) & ~(size_t)255;
    float* dinv = (float*)(ws + off);   off += (size_t)N * sizeof(float);
    off = (off + 255) & ~(size_t)255;
    int* rowptr = (int*)(ws + off);     off += (size_t)(N + 1) * sizeof(int);
    off = (off + 255) & ~(size_t)255;
    float* pstats2 = (float*)(ws + off); off += (size_t)PSLOT * 128 * sizeof(float);
    off = (off + 255) & ~(size_t)255;
    int* pk = (int*)(ws + off);         off += (size_t)E * sizeof(int);
    off = (off + 255) & ~(size_t)255;
    int* ssrc = (int*)(ws + off);       off += (size_t)E * sizeof(int);
    off = (off + 255) & ~(size_t)255;
    __half* h2 = (__half*)(ws + off);   off += (size_t)N * DIM * sizeof(__half);
    off = (off + 255) & ~(size_t)255;
    __half* a2 = (__half*)(ws + off);   off += (size_t)N * DIM * sizeof(__half);

    k_binhist<<<nbin, 256, 0, stream>>>(edst, bhist, donecnt, P, E);
    k_binscan<<<P, 128, 0, stream>>>(bhist, bintot, gbase, rowptr, donecnt, P, N, E, nbin);
    k_bin<<<nbin, 256, 0, stream>>>(esrc, edst, gbase, bhist, pk, P, E);
    k_sortrange<<<P, 256, 0, stream>>>(gbase, pk, ssrc, rowptr, dinv, N);
    k_gemm<<<(4 * N + 255) / 256, 256, 0, stream>>>(x, W, dinv, h2, pstats2, N);
    k_nodeagg<<<ABLK, 256, 0, stream>>>(rowptr, ssrc, h2, dinv, b, a2, pstats2, N);
    k_bn2<<<1024, 256, 0, stream>>>(a2, pstats2, gamma, beta, out, N * DIM / 8, N);
}

// Round 14
// 186.666 us; speedup vs baseline: 1.0295x; 1.0295x over previous
//
#include <hip/hip_runtime.h>
#include <hip/hip_fp16.h>

#define DIM 64
#define BN_EPS 1e-5f
#define RSHIFT 8          // 256 nodes per range
#define RSIZE 256
#define EPB 2048          // edges per bin block (489 blocks -> ~2/CU latency hiding)
#define ABLK 2048         // aggregation blocks (stats partials per block)
#define RBLK 128          // stage-1 reduction blocks (ABLK/RBLK partials each)
#define BH 512            // bhist row stride (bins per block record)

// ---------------- binhist: per-(block,bin) edge counts, no global atomics ----------------
// bhist[blk*BH + bin] = count of this block's edges landing in bin.
__global__ __launch_bounds__(256) void k_binhist(const int* __restrict__ dst,
                                                 int* __restrict__ bhist,
                                                 int P, int E) {
    __shared__ int hist[BH];
    for (int b0 = threadIdx.x; b0 < BH; b0 += 256) hist[b0] = 0;
    __syncthreads();
    const int base4 = blockIdx.x * (EPB / 4);
    for (int i = 0; i < EPB / 4 / 256; ++i) {
        int idx = base4 + i * 256 + threadIdx.x;
        int e0 = idx << 2;
        if (e0 + 3 < E) {
            int4 d4 = ((const int4*)dst)[idx];
            atomicAdd(&hist[d4.x >> RSHIFT], 1);
            atomicAdd(&hist[d4.y >> RSHIFT], 1);
            atomicAdd(&hist[d4.z >> RSHIFT], 1);
            atomicAdd(&hist[d4.w >> RSHIFT], 1);
        } else {
            for (int k = 0; k < 4; ++k)
                if (e0 + k < E) atomicAdd(&hist[dst[e0 + k] >> RSHIFT], 1);
        }
    }
    __syncthreads();
    for (int b0 = threadIdx.x; b0 < P; b0 += 256)
        bhist[blockIdx.x * BH + b0] = hist[b0];
}

// ---------------- binscan: per-bin parallel scan over blocks (grid = P bins) ----------------
// After: bhist[blk*BH+r] = exclusive prefix of bin r over blocks 0..blk-1; bintot[r] = bin total.
__global__ __launch_bounds__(128) void k_binscan(int* __restrict__ bhist,
                                                 int* __restrict__ bintot,
                                                 int nbin) {
    __shared__ int s[128];
    const int r = blockIdx.x;
    int carry = 0;
    for (int base = 0; base < nbin; base += 128) {
        const int idx = base + threadIdx.x;
        int v = (idx < nbin) ? bhist[idx * BH + r] : 0;
        s[threadIdx.x] = v;
        __syncthreads();
        for (int off = 1; off < 128; off <<= 1) {
            int t = (threadIdx.x >= (unsigned)off) ? s[threadIdx.x - off] : 0;
            __syncthreads();
            s[threadIdx.x] += t;
            __syncthreads();
        }
        if (idx < nbin) bhist[idx * BH + r] = carry + s[threadIdx.x] - v;
        carry += s[127];
        __syncthreads();
    }
    if (threadIdx.x == 0) bintot[r] = carry;
}

// ---------------- gscan: exclusive scan of bintot (P <= 512) -> gbase ----------------
__global__ void k_gscan(const int* __restrict__ bintot, int* __restrict__ gbase,
                        int* __restrict__ rowptr, int P, int N, int E) {
    __shared__ int s[512];
    int v = ((int)threadIdx.x < P) ? bintot[threadIdx.x] : 0;
    s[threadIdx.x] = v;
    __syncthreads();
    for (int off = 1; off < 512; off <<= 1) {
        int t = (threadIdx.x >= (unsigned)off) ? s[threadIdx.x - off] : 0;
        __syncthreads();
        s[threadIdx.x] += t;
        __syncthreads();
    }
    if ((int)threadIdx.x < P) gbase[threadIdx.x] = s[threadIdx.x] - v;
    if ((int)threadIdx.x == P - 1) gbase[P] = s[threadIdx.x];  // = E
    if (threadIdx.x == 0) rowptr[N] = E;
}

// ---------------- bin (single pass): group edges by dst-range into block-exclusive runs ----------------
// pk[pos] = (dstlocal << 20) | src   (src < 2^20, dstlocal < 256)
__global__ __launch_bounds__(256) void k_bin(const int* __restrict__ src,
                                             const int* __restrict__ dst,
                                             const int* __restrict__ gbase,
                                             const int* __restrict__ bhist,
                                             int* __restrict__ pk, int P, int E) {
    __shared__ int gofs[BH], lcnt[BH];
    for (int b0 = threadIdx.x; b0 < P; b0 += 256) {
        gofs[b0] = gbase[b0] + bhist[blockIdx.x * BH + b0];
        lcnt[b0] = 0;
    }
    __syncthreads();
    const int base4 = blockIdx.x * (EPB / 4);
    for (int i = 0; i < EPB / 4 / 256; ++i) {
        int idx = base4 + i * 256 + threadIdx.x;
        int e0 = idx << 2;
        if (e0 + 3 < E) {
            int4 d4 = ((const int4*)dst)[idx];
            int4 s4 = ((const int4*)src)[idx];
            int b0;
            b0 = d4.x >> RSHIFT; pk[gofs[b0] + atomicAdd(&lcnt[b0], 1)] = ((d4.x & (RSIZE - 1)) << 20) | s4.x;
            b0 = d4.y >> RSHIFT; pk[gofs[b0] + atomicAdd(&lcnt[b0], 1)] = ((d4.y & (RSIZE - 1)) << 20) | s4.y;
            b0 = d4.z >> RSHIFT; pk[gofs[b0] + atomicAdd(&lcnt[b0], 1)] = ((d4.z & (RSIZE - 1)) << 20) | s4.z;
            b0 = d4.w >> RSHIFT; pk[gofs[b0] + atomicAdd(&lcnt[b0], 1)] = ((d4.w & (RSIZE - 1)) << 20) | s4.w;
        } else {
            for (int k = 0; k < 4; ++k) {
                if (e0 + k < E) {
                    int d = dst[e0 + k];
                    int b0 = d >> RSHIFT;
                    pk[gofs[b0] + atomicAdd(&lcnt[b0], 1)] = ((d & (RSIZE - 1)) << 20) | src[e0 + k];
                }
            }
        }
    }
}

// ---------------- sortrange: per-range LDS counting sort; derives deg/dinv/rowptr ----------------
__global__ __launch_bounds__(256) void k_sortrange(
        const int* __restrict__ gbase, const int* __restrict__ pk,
        int* __restrict__ ssrc, int* __restrict__ rowptr,
        float* __restrict__ dinv, int N) {
    __shared__ int lhist[256], ls[256], lcur[256];
    const int r = blockIdx.x;
    const int d0 = r << RSHIFT;
    const int i = d0 + threadIdx.x;
    const int ebeg = gbase[r], eend = gbase[r + 1];
    lhist[threadIdx.x] = 0;
    __syncthreads();
    for (int j = ebeg + threadIdx.x; j < eend; j += 256)
        atomicAdd(&lhist[((unsigned)pk[j]) >> 20], 1);
    __syncthreads();
    int dg = lhist[threadIdx.x];
    if (i < N) dinv[i] = rsqrtf((float)dg + 1.0f);  // +1 self-loop
    ls[threadIdx.x] = dg;
    __syncthreads();
    for (int off = 1; off < 256; off <<= 1) {
        int t = (threadIdx.x >= (unsigned)off) ? ls[threadIdx.x - off] : 0;
        __syncthreads();
        ls[threadIdx.x] += t;
        __syncthreads();
    }
    int lofs = ls[threadIdx.x] - dg;  // local exclusive
    lcur[threadIdx.x] = ebeg + lofs;  // absolute cursor
    if (i < N) rowptr[i] = ebeg + lofs;
    __syncthreads();
    for (int j = ebeg + threadIdx.x; j < eend; j += 256) {
        int p = pk[j];
        ssrc[atomicAdd(&lcur[((unsigned)p) >> 20], 1)] = p & 0xFFFFF;
    }
}

// ---------------- gemm: 4 threads/row, 16 outputs each; emit h2 = fp16(h*dinv) only ----------------
__global__ __launch_bounds__(256) void k_gemm(const float* __restrict__ x,
                                              const float* __restrict__ W,
                                              const float* __restrict__ dinv,
                                              __half* __restrict__ h2, int N) {
    __shared__ float Wl[DIM * DIM];
    for (int i = threadIdx.x; i < DIM * DIM; i += 256) Wl[i] = W[i];
    __syncthreads();
    int t = blockIdx.x * 256 + threadIdx.x;
    int r = t >> 2;       // row
    int q = t & 3;        // output-feature quarter
    if (r >= N) return;
    const float4* xr4 = (const float4*)(x + (size_t)r * DIM);
    float4 acc[4];
#pragma unroll
    for (int j = 0; j < 4; ++j) acc[j] = make_float4(0.f, 0.f, 0.f, 0.f);
    for (int k0 = 0; k0 < 16; ++k0) {
        float4 xv = xr4[k0];
#pragma unroll
        for (int kk = 0; kk < 4; ++kk) {
            float xs = (&xv.x)[kk];
            const float4* wrow = (const float4*)(Wl + (k0 * 4 + kk) * DIM) + (q << 2);
#pragma unroll
            for (int j = 0; j < 4; ++j) {
                float4 w = wrow[j];
                acc[j].x += xs * w.x;
                acc[j].y += xs * w.y;
                acc[j].z += xs * w.z;
                acc[j].w += xs * w.w;
            }
        }
    }
    float dr = dinv[r];
    float4* hr4 = (float4*)(h2 + (size_t)r * DIM) + (q << 1);
    union { __half2 h[4]; float4 f4; } pack;
#pragma unroll
    for (int j = 0; j < 4; j += 2) {
        pack.h[0] = __float22half2_rn(make_float2(acc[j].x * dr, acc[j].y * dr));
        pack.h[1] = __float22half2_rn(make_float2(acc[j].z * dr, acc[j].w * dr));
        pack.h[2] = __float22half2_rn(make_float2(acc[j + 1].x * dr, acc[j + 1].y * dr));
        pack.h[3] = __float22half2_rn(make_float2(acc[j + 1].z * dr, acc[j + 1].w * dr));
        hr4[j >> 1] = pack.f4;
    }
}

// ---------------- nodeagg: node-PAIR pull (wave=2 nodes, lane=feature), NO atomics ----------------
// Combined contiguous edge range [rowptr[i0], rowptr[i0+2]) split by wave-uniform boundary.
// 16-deep gather batches for MLP. Writes a = relu((self+sum)*dinv+b) as fp16; BN partials.
__global__ __launch_bounds__(256) void k_nodeagg(
        const int* __restrict__ rowptr, const int* __restrict__ ssrc,
        const __half* __restrict__ h2, const float* __restrict__ dinv,
        const float* __restrict__ b, __half* __restrict__ a2,
        float* __restrict__ pstats, int N) {
    const int lane = threadIdx.x & 63;
    const int w = threadIdx.x >> 6;
    const float bl = b[lane];
    const __half* hb = h2 + lane;
    float psum = 0.f, psq = 0.f;
    const int npairs = N >> 1;  // N even (100000)
    for (int t = blockIdx.x * 4 + w; t < npairs; t += ABLK * 4) {
        const int i0 = t << 1;
        const int rb0 = rowptr[i0], rb1 = rowptr[i0 + 1], rb2 = rowptr[i0 + 2];
        float acc0 = __half2float(hb[(size_t)i0 * DIM]);        // self term node0
        float acc1 = __half2float(hb[(size_t)(i0 + 1) * DIM]);  // self term node1
        const int total = rb2 - rb0;
        for (int j0 = 0; j0 < total; j0 += 64) {
            const int m = min(64, total - j0);
            const int c = rb1 - rb0 - j0;   // local boundary (wave-uniform)
            int sv = ssrc[rb0 + j0 + min(lane, m - 1)];
            int j = 0;
            for (; j + 16 <= m; j += 16) {
                int sA[16];
                float vA[16];
#pragma unroll
                for (int k = 0; k < 16; ++k) sA[k] = __builtin_amdgcn_readlane(sv, j + k);
#pragma unroll
                for (int k = 0; k < 16; ++k) vA[k] = __half2float(hb[(size_t)sA[k] * DIM]);
#pragma unroll
                for (int k = 0; k < 16; ++k) {
                    if (j + k < c) acc0 += vA[k]; else acc1 += vA[k];
                }
            }
            if (j < m) {
                const int r = m - j;        // 1..15, wave-uniform
                int sA[16];
                float vA[16];
#pragma unroll
                for (int k = 0; k < 16; ++k) sA[k] = __builtin_amdgcn_readlane(sv, j + min(k, r - 1));
#pragma unroll
                for (int k = 0; k < 16; ++k) vA[k] = __half2float(hb[(size_t)sA[k] * DIM]);
#pragma unroll
                for (int k = 0; k < 16; ++k) {
                    if (k < r) { if (j + k < c) acc0 += vA[k]; else acc1 += vA[k]; }
                }
            }
        }
        float a0 = fmaxf(acc0 * dinv[i0] + bl, 0.f);
        float a1 = fmaxf(acc1 * dinv[i0 + 1] + bl, 0.f);
        a2[(size_t)i0 * DIM + lane] = __float2half_rn(a0);
        a2[(size_t)(i0 + 1) * DIM + lane] = __float2half_rn(a1);
        psum += a0 + a1;
        psq += a0 * a0 + a1 * a1;
    }
    __shared__ float s1[256], s2[256];
    s1[threadIdx.x] = psum;
    s2[threadIdx.x] = psq;
    __syncthreads();
    if (threadIdx.x < 128) {
        s1[threadIdx.x] += s1[threadIdx.x + 128];
        s2[threadIdx.x] += s2[threadIdx.x + 128];
    }
    __syncthreads();
    if (threadIdx.x < 64) {
        pstats[(size_t)blockIdx.x * 128 + threadIdx.x] = s1[threadIdx.x] + s1[threadIdx.x + 64];
        pstats[(size_t)blockIdx.x * 128 + 64 + threadIdx.x] = s2[threadIdx.x] + s2[threadIdx.x + 64];
    }
}

// ---------------- redstats: stage-1 parallel fold of ABLK partials -> RBLK partials ----------------
__global__ __launch_bounds__(128) void k_redstats(const float* __restrict__ pstats,
                                                  float* __restrict__ pstats2) {
    const int f = threadIdx.x;  // 0..127 (covers sum half and sq half uniformly)
    const size_t base = (size_t)blockIdx.x * (ABLK / RBLK) * 128;
    float s = 0.f;
#pragma unroll 8
    for (int j = 0; j < ABLK / RBLK; ++j)
        s += pstats[base + (size_t)j * 128 + f];
    pstats2[(size_t)blockIdx.x * 128 + f] = s;
}

// ---------------- finstats: reduce RBLK partials, emit scale/shift ----------------
__global__ void k_finstats(const float* __restrict__ pstats2,
                           const float* __restrict__ gamma, const float* __restrict__ beta,
                           float* __restrict__ scale, float* __restrict__ shift, int N) {
    __shared__ float ssum[1024], ssq[1024];
    const int f = threadIdx.x & 63;
    const int c = threadIdx.x >> 6;  // 0..15
    float s = 0.f, q = 0.f;
    for (int blk = c; blk < RBLK; blk += 16) {
        s += pstats2[blk * 128 + f];
        q += pstats2[blk * 128 + 64 + f];
    }
    ssum[threadIdx.x] = s;
    ssq[threadIdx.x] = q;
    __syncthreads();
    for (int o = 512; o >= 64; o >>= 1) {
        if ((int)threadIdx.x < o) {
            ssum[threadIdx.x] += ssum[threadIdx.x + o];
            ssq[threadIdx.x] += ssq[threadIdx.x + o];
        }
        __syncthreads();
    }
    if (threadIdx.x < 64) {
        float inv_n = 1.0f / (float)N;
        float mean = ssum[f] * inv_n;
        float var = ssq[f] * inv_n - mean * mean;
        float istd = rsqrtf(var + BN_EPS);
        float sc = gamma[f] * istd;
        scale[f] = sc;
        shift[f] = beta[f] - mean * sc;
    }
}

// ---------------- bn2: out = a2*scale + shift (a2 fp16, already relu'd) ----------------
__global__ void k_bn2(const __half* __restrict__ a2, const float* __restrict__ scale,
                      const float* __restrict__ shift, float* __restrict__ out, int total8) {
    int i = blockIdx.x * blockDim.x + threadIdx.x;
    const int stride = gridDim.x * blockDim.x;  // 262144 ≡ 0 (mod 8)
    const int f8 = i & 7;
    const float4 sc0 = ((const float4*)scale)[f8 * 2];
    const float4 sc1 = ((const float4*)scale)[f8 * 2 + 1];
    const float4 sh0 = ((const float4*)shift)[f8 * 2];
    const float4 sh1 = ((const float4*)shift)[f8 * 2 + 1];
    for (; i < total8; i += stride) {
        union { float4 f; __half2 h[4]; } u;
        u.f = ((const float4*)a2)[i];
        float2 p0 = __half22float2(u.h[0]);
        float2 p1 = __half22float2(u.h[1]);
        float2 p2 = __half22float2(u.h[2]);
        float2 p3 = __half22float2(u.h[3]);
        float4 o0 = make_float4(p0.x * sc0.x + sh0.x, p0.y * sc0.y + sh0.y,
                                p1.x * sc0.z + sh0.z, p1.y * sc0.w + sh0.w);
        float4 o1 = make_float4(p2.x * sc1.x + sh1.x, p2.y * sc1.y + sh1.y,
                                p3.x * sc1.z + sh1.z, p3.y * sc1.w + sh1.w);
        ((float4*)out)[(size_t)i * 2] = o0;
        ((float4*)out)[(size_t)i * 2 + 1] = o1;
    }
}

extern "C" void kernel_launch(void* const* d_in, const int* in_sizes, int n_in,
                              void* d_out, int out_size, void* d_ws, size_t ws_size,
                              hipStream_t stream) {
    const float* x     = (const float*)d_in[0];
    const int*   ei    = (const int*)d_in[1];
    const float* W     = (const float*)d_in[2];
    const float* b     = (const float*)d_in[3];
    const float* gamma = (const float*)d_in[4];
    const float* beta  = (const float*)d_in[5];
    float* out = (float*)d_out;

    const int N = in_sizes[0] / DIM;  // 100000
    const int E = in_sizes[1] / 2;    // 1000000
    const int* esrc = ei;
    const int* edst = ei + E;
    const int P = (N + RSIZE - 1) >> RSHIFT;   // 391 ranges (<= 512)
    const int nbin = (E + EPB - 1) / EPB;      // 489 bin blocks (<= 512)

    // workspace layout
    char* ws = (char*)d_ws;
    size_t off = 0;
    int* bhist = (int*)(ws + off);      off += (size_t)nbin * BH * sizeof(int);  // per-(block,bin) counts
    off = (off + 255) & ~(size_t)255;
    int* bintot = (int*)(ws + off);     off += 512 * sizeof(int);
    int* gbase = (int*)(ws + off);      off += 520 * sizeof(int);
    off = (off + 255) & ~(size_t)255;
    float* dinv = (float*)(ws + off);   off += (size_t)N * sizeof(float);
    off = (off + 255) & ~(size_t)255;
    int* rowptr = (int*)(ws + off);     off += (size_t)(N + 1) * sizeof(int);
    off = (off + 255) & ~(size_t)255;
    float* scale = (float*)(ws + off);  off += 64 * sizeof(float);
    float* shift = (float*)(ws + off);  off += 64 * sizeof(float);
    off = (off + 255) & ~(size_t)255;
    float* pstats = (float*)(ws + off); off += (size_t)ABLK * 128 * sizeof(float);
    off = (off + 255) & ~(size_t)255;
    float* pstats2 = (float*)(ws + off); off += (size_t)RBLK * 128 * sizeof(float);
    off = (off + 255) & ~(size_t)255;
    int* pk = (int*)(ws + off);         off += (size_t)E * sizeof(int);
    off = (off + 255) & ~(size_t)255;
    int* ssrc = (int*)(ws + off);       off += (size_t)E * sizeof(int);
    off = (off + 255) & ~(size_t)255;
    __half* h2 = (__half*)(ws + off);   off += (size_t)N * DIM * sizeof(__half);
    off = (off + 255) & ~(size_t)255;
    __half* a2 = (__half*)(ws + off);   off += (size_t)N * DIM * sizeof(__half);

    k_binhist<<<nbin, 256, 0, stream>>>(edst, bhist, P, E);
    k_binscan<<<P, 128, 0, stream>>>(bhist, bintot, nbin);
    k_gscan<<<1, 512, 0, stream>>>(bintot, gbase, rowptr, P, N, E);
    k_bin<<<nbin, 256, 0, stream>>>(esrc, edst, gbase, bhist, pk, P, E);
    k_sortrange<<<P, 256, 0, stream>>>(gbase, pk, ssrc, rowptr, dinv, N);
    k_gemm<<<(4 * N + 255) / 256, 256, 0, stream>>>(x, W, dinv, h2, N);
    k_nodeagg<<<ABLK, 256, 0, stream>>>(rowptr, ssrc, h2, dinv, b, a2, pstats, N);
    k_redstats<<<RBLK, 128, 0, stream>>>(pstats, pstats2);
    k_finstats<<<1, 1024, 0, stream>>>(pstats2, gamma, beta, scale, shift, N);
    k_bn2<<<1024, 256, 0, stream>>>(a2, scale, shift, out, N * DIM / 8);
}

// Round 15
// 183.679 us; speedup vs baseline: 1.0463x; 1.0163x over previous
//
#include <hip/hip_runtime.h>
#include <hip/hip_fp16.h>

#define DIM 64
#define BN_EPS 1e-5f
#define RSHIFT 8          // 256 nodes per range
#define RSIZE 256
#define EPB 2048          // edges per bin block
#define ABLK 2048         // aggregation blocks (stats partials per block)
#define RBLK 128          // stage-1 reduction blocks (ABLK/RBLK partials each)
#define BH 512            // bhist row stride (bins per block record)

// ---------------- binhist: per-(block,bin) edge counts, no global atomics ----------------
// bhist[blk*BH + bin] = count of this block's edges landing in bin.
__global__ __launch_bounds__(256) void k_binhist(const int* __restrict__ dst,
                                                 int* __restrict__ bhist,
                                                 int P, int E) {
    __shared__ int hist[BH];
    for (int b0 = threadIdx.x; b0 < BH; b0 += 256) hist[b0] = 0;
    __syncthreads();
    const int base4 = blockIdx.x * (EPB / 4);
    for (int i = 0; i < EPB / 4 / 256; ++i) {
        int idx = base4 + i * 256 + threadIdx.x;
        int e0 = idx << 2;
        if (e0 + 3 < E) {
            int4 d4 = ((const int4*)dst)[idx];
            atomicAdd(&hist[d4.x >> RSHIFT], 1);
            atomicAdd(&hist[d4.y >> RSHIFT], 1);
            atomicAdd(&hist[d4.z >> RSHIFT], 1);
            atomicAdd(&hist[d4.w >> RSHIFT], 1);
        } else {
            for (int k = 0; k < 4; ++k)
                if (e0 + k < E) atomicAdd(&hist[dst[e0 + k] >> RSHIFT], 1);
        }
    }
    __syncthreads();
    for (int b0 = threadIdx.x; b0 < P; b0 += 256)
        bhist[blockIdx.x * BH + b0] = hist[b0];
}

// ---------------- binscan: per-bin parallel scan over blocks (grid = P bins) ----------------
// After: bhist[blk*BH+r] = exclusive prefix of bin r over blocks 0..blk-1; bintot[r] = bin total.
__global__ __launch_bounds__(128) void k_binscan(int* __restrict__ bhist,
                                                 int* __restrict__ bintot,
                                                 int nbin) {
    __shared__ int s[128];
    const int r = blockIdx.x;
    int carry = 0;
    for (int base = 0; base < nbin; base += 128) {
        const int idx = base + threadIdx.x;
        int v = (idx < nbin) ? bhist[idx * BH + r] : 0;
        s[threadIdx.x] = v;
        __syncthreads();
        for (int off = 1; off < 128; off <<= 1) {
            int t = (threadIdx.x >= (unsigned)off) ? s[threadIdx.x - off] : 0;
            __syncthreads();
            s[threadIdx.x] += t;
            __syncthreads();
        }
        if (idx < nbin) bhist[idx * BH + r] = carry + s[threadIdx.x] - v;
        carry += s[127];
        __syncthreads();
    }
    if (threadIdx.x == 0) bintot[r] = carry;
}

// ---------------- gscan: exclusive scan of bintot (P <= 512) -> gbase ----------------
__global__ void k_gscan(const int* __restrict__ bintot, int* __restrict__ gbase,
                        int* __restrict__ rowptr, int P, int N, int E) {
    __shared__ int s[512];
    int v = ((int)threadIdx.x < P) ? bintot[threadIdx.x] : 0;
    s[threadIdx.x] = v;
    __syncthreads();
    for (int off = 1; off < 512; off <<= 1) {
        int t = (threadIdx.x >= (unsigned)off) ? s[threadIdx.x - off] : 0;
        __syncthreads();
        s[threadIdx.x] += t;
        __syncthreads();
    }
    if ((int)threadIdx.x < P) gbase[threadIdx.x] = s[threadIdx.x] - v;
    if ((int)threadIdx.x == P - 1) gbase[P] = s[threadIdx.x];  // = E
    if (threadIdx.x == 0) rowptr[N] = E;
}

// ---------------- bin (single pass): group edges by dst-range into block-exclusive runs ----------------
// pk[pos] = (dstlocal << 20) | src   (src < 2^20, dstlocal < 256)
__global__ __launch_bounds__(256) void k_bin(const int* __restrict__ src,
                                             const int* __restrict__ dst,
                                             const int* __restrict__ gbase,
                                             const int* __restrict__ bhist,
                                             int* __restrict__ pk, int P, int E) {
    __shared__ int gofs[BH], lcnt[BH];
    for (int b0 = threadIdx.x; b0 < P; b0 += 256) {
        gofs[b0] = gbase[b0] + bhist[blockIdx.x * BH + b0];
        lcnt[b0] = 0;
    }
    __syncthreads();
    const int base4 = blockIdx.x * (EPB / 4);
    for (int i = 0; i < EPB / 4 / 256; ++i) {
        int idx = base4 + i * 256 + threadIdx.x;
        int e0 = idx << 2;
        if (e0 + 3 < E) {
            int4 d4 = ((const int4*)dst)[idx];
            int4 s4 = ((const int4*)src)[idx];
            int b0;
            b0 = d4.x >> RSHIFT; pk[gofs[b0] + atomicAdd(&lcnt[b0], 1)] = ((d4.x & (RSIZE - 1)) << 20) | s4.x;
            b0 = d4.y >> RSHIFT; pk[gofs[b0] + atomicAdd(&lcnt[b0], 1)] = ((d4.y & (RSIZE - 1)) << 20) | s4.y;
            b0 = d4.z >> RSHIFT; pk[gofs[b0] + atomicAdd(&lcnt[b0], 1)] = ((d4.z & (RSIZE - 1)) << 20) | s4.z;
            b0 = d4.w >> RSHIFT; pk[gofs[b0] + atomicAdd(&lcnt[b0], 1)] = ((d4.w & (RSIZE - 1)) << 20) | s4.w;
        } else {
            for (int k = 0; k < 4; ++k) {
                if (e0 + k < E) {
                    int d = dst[e0 + k];
                    int b0 = d >> RSHIFT;
                    pk[gofs[b0] + atomicAdd(&lcnt[b0], 1)] = ((d & (RSIZE - 1)) << 20) | src[e0 + k];
                }
            }
        }
    }
}

// ---------------- sortrange: per-range LDS counting sort; derives deg/dinv/rowptr ----------------
__global__ __launch_bounds__(256) void k_sortrange(
        const int* __restrict__ gbase, const int* __restrict__ pk,
        int* __restrict__ ssrc, int* __restrict__ rowptr,
        float* __restrict__ dinv, int N) {
    __shared__ int lhist[256], ls[256], lcur[256];
    const int r = blockIdx.x;
    const int d0 = r << RSHIFT;
    const int i = d0 + threadIdx.x;
    const int ebeg = gbase[r], eend = gbase[r + 1];
    lhist[threadIdx.x] = 0;
    __syncthreads();
    for (int j = ebeg + threadIdx.x; j < eend; j += 256)
        atomicAdd(&lhist[((unsigned)pk[j]) >> 20], 1);
    __syncthreads();
    int dg = lhist[threadIdx.x];
    if (i < N) dinv[i] = rsqrtf((float)dg + 1.0f);  // +1 self-loop
    ls[threadIdx.x] = dg;
    __syncthreads();
    for (int off = 1; off < 256; off <<= 1) {
        int t = (threadIdx.x >= (unsigned)off) ? ls[threadIdx.x - off] : 0;
        __syncthreads();
        ls[threadIdx.x] += t;
        __syncthreads();
    }
    int lofs = ls[threadIdx.x] - dg;  // local exclusive
    lcur[threadIdx.x] = ebeg + lofs;  // absolute cursor
    if (i < N) rowptr[i] = ebeg + lofs;
    __syncthreads();
    for (int j = ebeg + threadIdx.x; j < eend; j += 256) {
        int p = pk[j];
        ssrc[atomicAdd(&lcur[((unsigned)p) >> 20], 1)] = p & 0xFFFFF;
    }
}

// ---------------- gemm: 4 threads/row, 16 outputs each; emit h2 = fp16(h*dinv) only ----------------
__global__ __launch_bounds__(256) void k_gemm(const float* __restrict__ x,
                                              const float* __restrict__ W,
                                              const float* __restrict__ dinv,
                                              __half* __restrict__ h2, int N) {
    __shared__ float Wl[DIM * DIM];
    for (int i = threadIdx.x; i < DIM * DIM; i += 256) Wl[i] = W[i];
    __syncthreads();
    int t = blockIdx.x * 256 + threadIdx.x;
    int r = t >> 2;       // row
    int q = t & 3;        // output-feature quarter
    if (r >= N) return;
    const float4* xr4 = (const float4*)(x + (size_t)r * DIM);
    float4 acc[4];
#pragma unroll
    for (int j = 0; j < 4; ++j) acc[j] = make_float4(0.f, 0.f, 0.f, 0.f);
    for (int k0 = 0; k0 < 16; ++k0) {
        float4 xv = xr4[k0];
#pragma unroll
        for (int kk = 0; kk < 4; ++kk) {
            float xs = (&xv.x)[kk];
            const float4* wrow = (const float4*)(Wl + (k0 * 4 + kk) * DIM) + (q << 2);
#pragma unroll
            for (int j = 0; j < 4; ++j) {
                float4 w = wrow[j];
                acc[j].x += xs * w.x;
                acc[j].y += xs * w.y;
                acc[j].z += xs * w.z;
                acc[j].w += xs * w.w;
            }
        }
    }
    float dr = dinv[r];
    float4* hr4 = (float4*)(h2 + (size_t)r * DIM) + (q << 1);
    union { __half2 h[4]; float4 f4; } pack;
#pragma unroll
    for (int j = 0; j < 4; j += 2) {
        pack.h[0] = __float22half2_rn(make_float2(acc[j].x * dr, acc[j].y * dr));
        pack.h[1] = __float22half2_rn(make_float2(acc[j].z * dr, acc[j].w * dr));
        pack.h[2] = __float22half2_rn(make_float2(acc[j + 1].x * dr, acc[j + 1].y * dr));
        pack.h[3] = __float22half2_rn(make_float2(acc[j + 1].z * dr, acc[j + 1].w * dr));
        hr4[j >> 1] = pack.f4;
    }
}

// ---------------- nodeagg: node-PAIR pull; 16/8/4/1 gather cascade (no clamp waste) ----------------
// Combined contiguous edge range [rowptr[i0], rowptr[i0+2]) split by wave-uniform boundary.
// Writes a = relu((self+sum)*dinv+b) as fp16; BN partials.
#define GATHER_BATCH(B)                                                             \
    {                                                                               \
        int sA[B]; float vA[B];                                                     \
        _Pragma("unroll")                                                           \
        for (int k = 0; k < B; ++k) sA[k] = __builtin_amdgcn_readlane(sv, j + k);   \
        _Pragma("unroll")                                                           \
        for (int k = 0; k < B; ++k) vA[k] = __half2float(hb[(size_t)sA[k] * DIM]);  \
        _Pragma("unroll")                                                           \
        for (int k = 0; k < B; ++k) {                                               \
            if (j + k < c) acc0 += vA[k]; else acc1 += vA[k];                       \
        }                                                                           \
        j += B;                                                                     \
    }

__global__ __launch_bounds__(256) void k_nodeagg(
        const int* __restrict__ rowptr, const int* __restrict__ ssrc,
        const __half* __restrict__ h2, const float* __restrict__ dinv,
        const float* __restrict__ b, __half* __restrict__ a2,
        float* __restrict__ pstats, int N) {
    const int lane = threadIdx.x & 63;
    const int w = threadIdx.x >> 6;
    const float bl = b[lane];
    const __half* hb = h2 + lane;
    float psum = 0.f, psq = 0.f;
    const int npairs = N >> 1;  // N even (100000)
    for (int t = blockIdx.x * 4 + w; t < npairs; t += ABLK * 4) {
        const int i0 = t << 1;
        const int rb0 = rowptr[i0], rb1 = rowptr[i0 + 1], rb2 = rowptr[i0 + 2];
        float acc0 = __half2float(hb[(size_t)i0 * DIM]);        // self term node0
        float acc1 = __half2float(hb[(size_t)(i0 + 1) * DIM]);  // self term node1
        const int total = rb2 - rb0;
        for (int j0 = 0; j0 < total; j0 += 64) {
            const int m = min(64, total - j0);
            const int c = rb1 - rb0 - j0;   // local boundary (wave-uniform)
            int sv = ssrc[rb0 + j0 + min(lane, m - 1)];
            int j = 0;
            while (j + 16 <= m) GATHER_BATCH(16)
            if (j + 8 <= m) GATHER_BATCH(8)
            if (j + 4 <= m) GATHER_BATCH(4)
            for (; j < m; ++j) {
                int sj = __builtin_amdgcn_readlane(sv, j);
                float v = __half2float(hb[(size_t)sj * DIM]);
                if (j < c) acc0 += v; else acc1 += v;
            }
        }
        float a0 = fmaxf(acc0 * dinv[i0] + bl, 0.f);
        float a1 = fmaxf(acc1 * dinv[i0 + 1] + bl, 0.f);
        a2[(size_t)i0 * DIM + lane] = __float2half_rn(a0);
        a2[(size_t)(i0 + 1) * DIM + lane] = __float2half_rn(a1);
        psum += a0 + a1;
        psq += a0 * a0 + a1 * a1;
    }
    __shared__ float s1[256], s2[256];
    s1[threadIdx.x] = psum;
    s2[threadIdx.x] = psq;
    __syncthreads();
    if (threadIdx.x < 128) {
        s1[threadIdx.x] += s1[threadIdx.x + 128];
        s2[threadIdx.x] += s2[threadIdx.x + 128];
    }
    __syncthreads();
    if (threadIdx.x < 64) {
        pstats[(size_t)blockIdx.x * 128 + threadIdx.x] = s1[threadIdx.x] + s1[threadIdx.x + 64];
        pstats[(size_t)blockIdx.x * 128 + 64 + threadIdx.x] = s2[threadIdx.x] + s2[threadIdx.x + 64];
    }
}

// ---------------- redstats: stage-1 parallel fold of ABLK partials -> RBLK partials ----------------
__global__ __launch_bounds__(128) void k_redstats(const float* __restrict__ pstats,
                                                  float* __restrict__ pstats2) {
    const int f = threadIdx.x;  // 0..127 (covers sum half and sq half uniformly)
    const size_t base = (size_t)blockIdx.x * (ABLK / RBLK) * 128;
    float s = 0.f;
#pragma unroll 8
    for (int j = 0; j < ABLK / RBLK; ++j)
        s += pstats[base + (size_t)j * 128 + f];
    pstats2[(size_t)blockIdx.x * 128 + f] = s;
}

// ---------------- finstats: reduce RBLK partials, emit scale/shift ----------------
__global__ void k_finstats(const float* __restrict__ pstats2,
                           const float* __restrict__ gamma, const float* __restrict__ beta,
                           float* __restrict__ scale, float* __restrict__ shift, int N) {
    __shared__ float ssum[1024], ssq[1024];
    const int f = threadIdx.x & 63;
    const int c = threadIdx.x >> 6;  // 0..15
    float s = 0.f, q = 0.f;
    for (int blk = c; blk < RBLK; blk += 16) {
        s += pstats2[blk * 128 + f];
        q += pstats2[blk * 128 + 64 + f];
    }
    ssum[threadIdx.x] = s;
    ssq[threadIdx.x] = q;
    __syncthreads();
    for (int o = 512; o >= 64; o >>= 1) {
        if ((int)threadIdx.x < o) {
            ssum[threadIdx.x] += ssum[threadIdx.x + o];
            ssq[threadIdx.x] += ssq[threadIdx.x + o];
        }
        __syncthreads();
    }
    if (threadIdx.x < 64) {
        float inv_n = 1.0f / (float)N;
        float mean = ssum[f] * inv_n;
        float var = ssq[f] * inv_n - mean * mean;
        float istd = rsqrtf(var + BN_EPS);
        float sc = gamma[f] * istd;
        scale[f] = sc;
        shift[f] = beta[f] - mean * sc;
    }
}

// ---------------- bn2: out = a2*scale + shift (a2 fp16, already relu'd) ----------------
__global__ void k_bn2(const __half* __restrict__ a2, const float* __restrict__ scale,
                      const float* __restrict__ shift, float* __restrict__ out, int total8) {
    int i = blockIdx.x * blockDim.x + threadIdx.x;
    const int stride = gridDim.x * blockDim.x;  // 262144 ≡ 0 (mod 8)
    const int f8 = i & 7;
    const float4 sc0 = ((const float4*)scale)[f8 * 2];
    const float4 sc1 = ((const float4*)scale)[f8 * 2 + 1];
    const float4 sh0 = ((const float4*)shift)[f8 * 2];
    const float4 sh1 = ((const float4*)shift)[f8 * 2 + 1];
    for (; i < total8; i += stride) {
        union { float4 f; __half2 h[4]; } u;
        u.f = ((const float4*)a2)[i];
        float2 p0 = __half22float2(u.h[0]);
        float2 p1 = __half22float2(u.h[1]);
        float2 p2 = __half22float2(u.h[2]);
        float2 p3 = __half22float2(u.h[3]);
        float4 o0 = make_float4(p0.x * sc0.x + sh0.x, p0.y * sc0.y + sh0.y,
                                p1.x * sc0.z + sh0.z, p1.y * sc0.w + sh0.w);
        float4 o1 = make_float4(p2.x * sc1.x + sh1.x, p2.y * sc1.y + sh1.y,
                                p3.x * sc1.z + sh1.z, p3.y * sc1.w + sh1.w);
        ((float4*)out)[(size_t)i * 2] = o0;
        ((float4*)out)[(size_t)i * 2 + 1] = o1;
    }
}

extern "C" void kernel_launch(void* const* d_in, const int* in_sizes, int n_in,
                              void* d_out, int out_size, void* d_ws, size_t ws_size,
                              hipStream_t stream) {
    const float* x     = (const float*)d_in[0];
    const int*   ei    = (const int*)d_in[1];
    const float* W     = (const float*)d_in[2];
    const float* b     = (const float*)d_in[3];
    const float* gamma = (const float*)d_in[4];
    const float* beta  = (const float*)d_in[5];
    float* out = (float*)d_out;

    const int N = in_sizes[0] / DIM;  // 100000
    const int E = in_sizes[1] / 2;    // 1000000
    const int* esrc = ei;
    const int* edst = ei + E;
    const int P = (N + RSIZE - 1) >> RSHIFT;   // 391 ranges (<= 512)
    const int nbin = (E + EPB - 1) / EPB;      // 489 bin blocks (<= 512)

    // workspace layout
    char* ws = (char*)d_ws;
    size_t off = 0;
    int* bhist = (int*)(ws + off);      off += (size_t)nbin * BH * sizeof(int);  // per-(block,bin) counts
    off = (off + 255) & ~(size_t)255;
    int* bintot = (int*)(ws + off);     off += 512 * sizeof(int);
    int* gbase = (int*)(ws + off);      off += 520 * sizeof(int);
    off = (off + 255) & ~(size_t)255;
    float* dinv = (float*)(ws + off);   off += (size_t)N * sizeof(float);
    off = (off + 255) & ~(size_t)255;
    int* rowptr = (int*)(ws + off);     off += (size_t)(N + 1) * sizeof(int);
    off = (off + 255) & ~(size_t)255;
    float* scale = (float*)(ws + off);  off += 64 * sizeof(float);
    float* shift = (float*)(ws + off);  off += 64 * sizeof(float);
    off = (off + 255) & ~(size_t)255;
    float* pstats = (float*)(ws + off); off += (size_t)ABLK * 128 * sizeof(float);
    off = (off + 255) & ~(size_t)255;
    float* pstats2 = (float*)(ws + off); off += (size_t)RBLK * 128 * sizeof(float);
    off = (off + 255) & ~(size_t)255;
    int* pk = (int*)(ws + off);         off += (size_t)E * sizeof(int);
    off = (off + 255) & ~(size_t)255;
    int* ssrc = (int*)(ws + off);       off += (size_t)E * sizeof(int);
    off = (off + 255) & ~(size_t)255;
    __half* h2 = (__half*)(ws + off);   off += (size_t)N * DIM * sizeof(__half);
    off = (off + 255) & ~(size_t)255;
    __half* a2 = (__half*)(ws + off);   off += (size_t)N * DIM * sizeof(__half);

    k_binhist<<<nbin, 256, 0, stream>>>(edst, bhist, P, E);
    k_binscan<<<P, 128, 0, stream>>>(bhist, bintot, nbin);
    k_gscan<<<1, 512, 0, stream>>>(bintot, gbase, rowptr, P, N, E);
    k_bin<<<nbin, 256, 0, stream>>>(esrc, edst, gbase, bhist, pk, P, E);
    k_sortrange<<<P, 256, 0, stream>>>(gbase, pk, ssrc, rowptr, dinv, N);
    k_gemm<<<(4 * N + 255) / 256, 256, 0, stream>>>(x, W, dinv, h2, N);
    k_nodeagg<<<ABLK, 256, 0, stream>>>(rowptr, ssrc, h2, dinv, b, a2, pstats, N);
    k_redstats<<<RBLK, 128, 0, stream>>>(pstats, pstats2);
    k_finstats<<<1, 1024, 0, stream>>>(pstats2, gamma, beta, scale, shift, N);
    k_bn2<<<1024, 256, 0, stream>>>(a2, scale, shift, out, N * DIM / 8);
}

// Round 16
// 181.498 us; speedup vs baseline: 1.0589x; 1.0120x over previous
//
#include <hip/hip_runtime.h>
#include <hip/hip_fp16.h>

#define DIM 64
#define BN_EPS 1e-5f
#define RSHIFT 8          // 256 nodes per range
#define RSIZE 256
#define EPB 2048          // edges per bin block
#define ABLK 2048         // aggregation blocks (stats partials per block)
#define RBLK 128          // stage-1 reduction blocks (ABLK/RBLK partials each)
#define BH 512            // bhist row stride (bins per block record)

// ---------------- binhist: per-(block,bin) edge counts, no global atomics ----------------
// bhist[blk*BH + bin] = count of this block's edges landing in bin.
__global__ __launch_bounds__(256) void k_binhist(const int* __restrict__ dst,
                                                 int* __restrict__ bhist,
                                                 int P, int E) {
    __shared__ int hist[BH];
    for (int b0 = threadIdx.x; b0 < BH; b0 += 256) hist[b0] = 0;
    __syncthreads();
    const int base4 = blockIdx.x * (EPB / 4);
    for (int i = 0; i < EPB / 4 / 256; ++i) {
        int idx = base4 + i * 256 + threadIdx.x;
        int e0 = idx << 2;
        if (e0 + 3 < E) {
            int4 d4 = ((const int4*)dst)[idx];
            atomicAdd(&hist[d4.x >> RSHIFT], 1);
            atomicAdd(&hist[d4.y >> RSHIFT], 1);
            atomicAdd(&hist[d4.z >> RSHIFT], 1);
            atomicAdd(&hist[d4.w >> RSHIFT], 1);
        } else {
            for (int k = 0; k < 4; ++k)
                if (e0 + k < E) atomicAdd(&hist[dst[e0 + k] >> RSHIFT], 1);
        }
    }
    __syncthreads();
    for (int b0 = threadIdx.x; b0 < P; b0 += 256)
        bhist[blockIdx.x * BH + b0] = hist[b0];
}

// ---------------- binscan: per-bin parallel scan over blocks (grid = P bins) ----------------
// After: bhist[blk*BH+r] = exclusive prefix of bin r over blocks 0..blk-1; bintot[r] = bin total.
__global__ __launch_bounds__(128) void k_binscan(int* __restrict__ bhist,
                                                 int* __restrict__ bintot,
                                                 int nbin) {
    __shared__ int s[128];
    const int r = blockIdx.x;
    int carry = 0;
    for (int base = 0; base < nbin; base += 128) {
        const int idx = base + threadIdx.x;
        int v = (idx < nbin) ? bhist[idx * BH + r] : 0;
        s[threadIdx.x] = v;
        __syncthreads();
        for (int off = 1; off < 128; off <<= 1) {
            int t = (threadIdx.x >= (unsigned)off) ? s[threadIdx.x - off] : 0;
            __syncthreads();
            s[threadIdx.x] += t;
            __syncthreads();
        }
        if (idx < nbin) bhist[idx * BH + r] = carry + s[threadIdx.x] - v;
        carry += s[127];
        __syncthreads();
    }
    if (threadIdx.x == 0) bintot[r] = carry;
}

// ---------------- gscan: exclusive scan of bintot (P <= 512) -> gbase ----------------
__global__ void k_gscan(const int* __restrict__ bintot, int* __restrict__ gbase,
                        int* __restrict__ rowptr, int P, int N, int E) {
    __shared__ int s[512];
    int v = ((int)threadIdx.x < P) ? bintot[threadIdx.x] : 0;
    s[threadIdx.x] = v;
    __syncthreads();
    for (int off = 1; off < 512; off <<= 1) {
        int t = (threadIdx.x >= (unsigned)off) ? s[threadIdx.x - off] : 0;
        __syncthreads();
        s[threadIdx.x] += t;
        __syncthreads();
    }
    if ((int)threadIdx.x < P) gbase[threadIdx.x] = s[threadIdx.x] - v;
    if ((int)threadIdx.x == P - 1) gbase[P] = s[threadIdx.x];  // = E
    if (threadIdx.x == 0) rowptr[N] = E;
}

// ---------------- bin (single pass): group edges by dst-range into block-exclusive runs ----------------
// pk[pos] = (dstlocal << 20) | src   (src < 2^20, dstlocal < 256)
__global__ __launch_bounds__(256) void k_bin(const int* __restrict__ src,
                                             const int* __restrict__ dst,
                                             const int* __restrict__ gbase,
                                             const int* __restrict__ bhist,
                                             int* __restrict__ pk, int P, int E) {
    __shared__ int gofs[BH], lcnt[BH];
    for (int b0 = threadIdx.x; b0 < P; b0 += 256) {
        gofs[b0] = gbase[b0] + bhist[blockIdx.x * BH + b0];
        lcnt[b0] = 0;
    }
    __syncthreads();
    const int base4 = blockIdx.x * (EPB / 4);
    for (int i = 0; i < EPB / 4 / 256; ++i) {
        int idx = base4 + i * 256 + threadIdx.x;
        int e0 = idx << 2;
        if (e0 + 3 < E) {
            int4 d4 = ((const int4*)dst)[idx];
            int4 s4 = ((const int4*)src)[idx];
            int b0;
            b0 = d4.x >> RSHIFT; pk[gofs[b0] + atomicAdd(&lcnt[b0], 1)] = ((d4.x & (RSIZE - 1)) << 20) | s4.x;
            b0 = d4.y >> RSHIFT; pk[gofs[b0] + atomicAdd(&lcnt[b0], 1)] = ((d4.y & (RSIZE - 1)) << 20) | s4.y;
            b0 = d4.z >> RSHIFT; pk[gofs[b0] + atomicAdd(&lcnt[b0], 1)] = ((d4.z & (RSIZE - 1)) << 20) | s4.z;
            b0 = d4.w >> RSHIFT; pk[gofs[b0] + atomicAdd(&lcnt[b0], 1)] = ((d4.w & (RSIZE - 1)) << 20) | s4.w;
        } else {
            for (int k = 0; k < 4; ++k) {
                if (e0 + k < E) {
                    int d = dst[e0 + k];
                    int b0 = d >> RSHIFT;
                    pk[gofs[b0] + atomicAdd(&lcnt[b0], 1)] = ((d & (RSIZE - 1)) << 20) | src[e0 + k];
                }
            }
        }
    }
}

// ---------------- sortrange: per-range LDS counting sort (512 threads for latency hiding) ----------------
__global__ __launch_bounds__(512) void k_sortrange(
        const int* __restrict__ gbase, const int* __restrict__ pk,
        int* __restrict__ ssrc, int* __restrict__ rowptr,
        float* __restrict__ dinv, int N) {
    __shared__ int lhist[256], ls[256], lcur[256];
    const int r = blockIdx.x;
    const int d0 = r << RSHIFT;
    const int tid = threadIdx.x;
    const int i = d0 + tid;   // valid only for tid < 256
    const int ebeg = gbase[r], eend = gbase[r + 1];
    if (tid < 256) lhist[tid] = 0;
    __syncthreads();
    for (int j = ebeg + tid; j < eend; j += 512)
        atomicAdd(&lhist[((unsigned)pk[j]) >> 20], 1);
    __syncthreads();
    int dg = 0;
    if (tid < 256) {
        dg = lhist[tid];
        if (i < N) dinv[i] = rsqrtf((float)dg + 1.0f);  // +1 self-loop
        ls[tid] = dg;
    }
    __syncthreads();
    for (int off = 1; off < 256; off <<= 1) {
        int t = (tid < 256 && tid >= off) ? ls[tid - off] : 0;
        __syncthreads();
        if (tid < 256) ls[tid] += t;
        __syncthreads();
    }
    if (tid < 256) {
        int lofs = ls[tid] - dg;      // local exclusive
        lcur[tid] = ebeg + lofs;      // absolute cursor
        if (i < N) rowptr[i] = ebeg + lofs;
    }
    __syncthreads();
    for (int j = ebeg + tid; j < eend; j += 512) {
        int p = pk[j];
        ssrc[atomicAdd(&lcur[((unsigned)p) >> 20], 1)] = p & 0xFFFFF;
    }
}

// ---------------- gemm: 4 threads/row, 16 outputs each; emit h2 = fp16(h*dinv) only ----------------
__global__ __launch_bounds__(256) void k_gemm(const float* __restrict__ x,
                                              const float* __restrict__ W,
                                              const float* __restrict__ dinv,
                                              __half* __restrict__ h2, int N) {
    __shared__ float Wl[DIM * DIM];
    for (int i = threadIdx.x; i < DIM * DIM; i += 256) Wl[i] = W[i];
    __syncthreads();
    int t = blockIdx.x * 256 + threadIdx.x;
    int r = t >> 2;       // row
    int q = t & 3;        // output-feature quarter
    if (r >= N) return;
    const float4* xr4 = (const float4*)(x + (size_t)r * DIM);
    float4 acc[4];
#pragma unroll
    for (int j = 0; j < 4; ++j) acc[j] = make_float4(0.f, 0.f, 0.f, 0.f);
    for (int k0 = 0; k0 < 16; ++k0) {
        float4 xv = xr4[k0];
#pragma unroll
        for (int kk = 0; kk < 4; ++kk) {
            float xs = (&xv.x)[kk];
            const float4* wrow = (const float4*)(Wl + (k0 * 4 + kk) * DIM) + (q << 2);
#pragma unroll
            for (int j = 0; j < 4; ++j) {
                float4 w = wrow[j];
                acc[j].x += xs * w.x;
                acc[j].y += xs * w.y;
                acc[j].z += xs * w.z;
                acc[j].w += xs * w.w;
            }
        }
    }
    float dr = dinv[r];
    float4* hr4 = (float4*)(h2 + (size_t)r * DIM) + (q << 1);
    union { __half2 h[4]; float4 f4; } pack;
#pragma unroll
    for (int j = 0; j < 4; j += 2) {
        pack.h[0] = __float22half2_rn(make_float2(acc[j].x * dr, acc[j].y * dr));
        pack.h[1] = __float22half2_rn(make_float2(acc[j].z * dr, acc[j].w * dr));
        pack.h[2] = __float22half2_rn(make_float2(acc[j + 1].x * dr, acc[j + 1].y * dr));
        pack.h[3] = __float22half2_rn(make_float2(acc[j + 1].z * dr, acc[j + 1].w * dr));
        hr4[j >> 1] = pack.f4;
    }
}

// ---------------- nodeagg: node-PAIR pull; 16/8/4/1 gather cascade (no clamp waste) ----------------
// Combined contiguous edge range [rowptr[i0], rowptr[i0+2]) split by wave-uniform boundary.
// Writes a = relu((self+sum)*dinv+b) as fp16; BN partials.
#define GATHER_BATCH(B)                                                             \
    {                                                                               \
        int sA[B]; float vA[B];                                                     \
        _Pragma("unroll")                                                           \
        for (int k = 0; k < B; ++k) sA[k] = __builtin_amdgcn_readlane(sv, j + k);   \
        _Pragma("unroll")                                                           \
        for (int k = 0; k < B; ++k) vA[k] = __half2float(hb[(size_t)sA[k] * DIM]);  \
        _Pragma("unroll")                                                           \
        for (int k = 0; k < B; ++k) {                                               \
            if (j + k < c) acc0 += vA[k]; else acc1 += vA[k];                       \
        }                                                                           \
        j += B;                                                                     \
    }

__global__ __launch_bounds__(256) void k_nodeagg(
        const int* __restrict__ rowptr, const int* __restrict__ ssrc,
        const __half* __restrict__ h2, const float* __restrict__ dinv,
        const float* __restrict__ b, __half* __restrict__ a2,
        float* __restrict__ pstats, int N) {
    const int lane = threadIdx.x & 63;
    const int w = threadIdx.x >> 6;
    const float bl = b[lane];
    const __half* hb = h2 + lane;
    float psum = 0.f, psq = 0.f;
    const int npairs = N >> 1;  // N even (100000)
    for (int t = blockIdx.x * 4 + w; t < npairs; t += ABLK * 4) {
        const int i0 = t << 1;
        const int rb0 = rowptr[i0], rb1 = rowptr[i0 + 1], rb2 = rowptr[i0 + 2];
        float acc0 = __half2float(hb[(size_t)i0 * DIM]);        // self term node0
        float acc1 = __half2float(hb[(size_t)(i0 + 1) * DIM]);  // self term node1
        const int total = rb2 - rb0;
        for (int j0 = 0; j0 < total; j0 += 64) {
            const int m = min(64, total - j0);
            const int c = rb1 - rb0 - j0;   // local boundary (wave-uniform)
            int sv = ssrc[rb0 + j0 + min(lane, m - 1)];
            int j = 0;
            while (j + 16 <= m) GATHER_BATCH(16)
            if (j + 8 <= m) GATHER_BATCH(8)
            if (j + 4 <= m) GATHER_BATCH(4)
            for (; j < m; ++j) {
                int sj = __builtin_amdgcn_readlane(sv, j);
                float v = __half2float(hb[(size_t)sj * DIM]);
                if (j < c) acc0 += v; else acc1 += v;
            }
        }
        float a0 = fmaxf(acc0 * dinv[i0] + bl, 0.f);
        float a1 = fmaxf(acc1 * dinv[i0 + 1] + bl, 0.f);
        a2[(size_t)i0 * DIM + lane] = __float2half_rn(a0);
        a2[(size_t)(i0 + 1) * DIM + lane] = __float2half_rn(a1);
        psum += a0 + a1;
        psq += a0 * a0 + a1 * a1;
    }
    __shared__ float s1[256], s2[256];
    s1[threadIdx.x] = psum;
    s2[threadIdx.x] = psq;
    __syncthreads();
    if (threadIdx.x < 128) {
        s1[threadIdx.x] += s1[threadIdx.x + 128];
        s2[threadIdx.x] += s2[threadIdx.x + 128];
    }
    __syncthreads();
    if (threadIdx.x < 64) {
        pstats[(size_t)blockIdx.x * 128 + threadIdx.x] = s1[threadIdx.x] + s1[threadIdx.x + 64];
        pstats[(size_t)blockIdx.x * 128 + 64 + threadIdx.x] = s2[threadIdx.x] + s2[threadIdx.x + 64];
    }
}

// ---------------- redstats: stage-1 parallel fold of ABLK partials -> RBLK partials ----------------
__global__ __launch_bounds__(128) void k_redstats(const float* __restrict__ pstats,
                                                  float* __restrict__ pstats2) {
    const int f = threadIdx.x;  // 0..127 (covers sum half and sq half uniformly)
    const size_t base = (size_t)blockIdx.x * (ABLK / RBLK) * 128;
    float s = 0.f;
#pragma unroll 8
    for (int j = 0; j < ABLK / RBLK; ++j)
        s += pstats[base + (size_t)j * 128 + f];
    pstats2[(size_t)blockIdx.x * 128 + f] = s;
}

// ---------------- finstats: reduce RBLK partials, emit scale/shift ----------------
__global__ void k_finstats(const float* __restrict__ pstats2,
                           const float* __restrict__ gamma, const float* __restrict__ beta,
                           float* __restrict__ scale, float* __restrict__ shift, int N) {
    __shared__ float ssum[1024], ssq[1024];
    const int f = threadIdx.x & 63;
    const int c = threadIdx.x >> 6;  // 0..15
    float s = 0.f, q = 0.f;
    for (int blk = c; blk < RBLK; blk += 16) {
        s += pstats2[blk * 128 + f];
        q += pstats2[blk * 128 + 64 + f];
    }
    ssum[threadIdx.x] = s;
    ssq[threadIdx.x] = q;
    __syncthreads();
    for (int o = 512; o >= 64; o >>= 1) {
        if ((int)threadIdx.x < o) {
            ssum[threadIdx.x] += ssum[threadIdx.x + o];
            ssq[threadIdx.x] += ssq[threadIdx.x + o];
        }
        __syncthreads();
    }
    if (threadIdx.x < 64) {
        float inv_n = 1.0f / (float)N;
        float mean = ssum[f] * inv_n;
        float var = ssq[f] * inv_n - mean * mean;
        float istd = rsqrtf(var + BN_EPS);
        float sc = gamma[f] * istd;
        scale[f] = sc;
        shift[f] = beta[f] - mean * sc;
    }
}

// ---------------- bn2: out = a2*scale + shift (a2 fp16, already relu'd) ----------------
__global__ void k_bn2(const __half* __restrict__ a2, const float* __restrict__ scale,
                      const float* __restrict__ shift, float* __restrict__ out, int total8) {
    int i = blockIdx.x * blockDim.x + threadIdx.x;
    const int stride = gridDim.x * blockDim.x;  // 262144 ≡ 0 (mod 8)
    const int f8 = i & 7;
    const float4 sc0 = ((const float4*)scale)[f8 * 2];
    const float4 sc1 = ((const float4*)scale)[f8 * 2 + 1];
    const float4 sh0 = ((const float4*)shift)[f8 * 2];
    const float4 sh1 = ((const float4*)shift)[f8 * 2 + 1];
    for (; i < total8; i += stride) {
        union { float4 f; __half2 h[4]; } u;
        u.f = ((const float4*)a2)[i];
        float2 p0 = __half22float2(u.h[0]);
        float2 p1 = __half22float2(u.h[1]);
        float2 p2 = __half22float2(u.h[2]);
        float2 p3 = __half22float2(u.h[3]);
        float4 o0 = make_float4(p0.x * sc0.x + sh0.x, p0.y * sc0.y + sh0.y,
                                p1.x * sc0.z + sh0.z, p1.y * sc0.w + sh0.w);
        float4 o1 = make_float4(p2.x * sc1.x + sh1.x, p2.y * sc1.y + sh1.y,
                                p3.x * sc1.z + sh1.z, p3.y * sc1.w + sh1.w);
        ((float4*)out)[(size_t)i * 2] = o0;
        ((float4*)out)[(size_t)i * 2 + 1] = o1;
    }
}

extern "C" void kernel_launch(void* const* d_in, const int* in_sizes, int n_in,
                              void* d_out, int out_size, void* d_ws, size_t ws_size,
                              hipStream_t stream) {
    const float* x     = (const float*)d_in[0];
    const int*   ei    = (const int*)d_in[1];
    const float* W     = (const float*)d_in[2];
    const float* b     = (const float*)d_in[3];
    const float* gamma = (const float*)d_in[4];
    const float* beta  = (const float*)d_in[5];
    float* out = (float*)d_out;

    const int N = in_sizes[0] / DIM;  // 100000
    const int E = in_sizes[1] / 2;    // 1000000
    const int* esrc = ei;
    const int* edst = ei + E;
    const int P = (N + RSIZE - 1) >> RSHIFT;   // 391 ranges (<= 512)
    const int nbin = (E + EPB - 1) / EPB;      // 489 bin blocks (<= 512)

    // workspace layout
    char* ws = (char*)d_ws;
    size_t off = 0;
    int* bhist = (int*)(ws + off);      off += (size_t)nbin * BH * sizeof(int);  // per-(block,bin) counts
    off = (off + 255) & ~(size_t)255;
    int* bintot = (int*)(ws + off);     off += 512 * sizeof(int);
    int* gbase = (int*)(ws + off);      off += 520 * sizeof(int);
    off = (off + 255) & ~(size_t)255;
    float* dinv = (float*)(ws + off);   off += (size_t)N * sizeof(float);
    off = (off + 255) & ~(size_t)255;
    int* rowptr = (int*)(ws + off);     off += (size_t)(N + 1) * sizeof(int);
    off = (off + 255) & ~(size_t)255;
    float* scale = (float*)(ws + off);  off += 64 * sizeof(float);
    float* shift = (float*)(ws + off);  off += 64 * sizeof(float);
    off = (off + 255) & ~(size_t)255;
    float* pstats = (float*)(ws + off); off += (size_t)ABLK * 128 * sizeof(float);
    off = (off + 255) & ~(size_t)255;
    float* pstats2 = (float*)(ws + off); off += (size_t)RBLK * 128 * sizeof(float);
    off = (off + 255) & ~(size_t)255;
    int* pk = (int*)(ws + off);         off += (size_t)E * sizeof(int);
    off = (off + 255) & ~(size_t)255;
    int* ssrc = (int*)(ws + off);       off += (size_t)E * sizeof(int);
    off = (off + 255) & ~(size_t)255;
    __half* h2 = (__half*)(ws + off);   off += (size_t)N * DIM * sizeof(__half);
    off = (off + 255) & ~(size_t)255;
    __half* a2 = (__half*)(ws + off);   off += (size_t)N * DIM * sizeof(__half);

    k_binhist<<<nbin, 256, 0, stream>>>(edst, bhist, P, E);
    k_binscan<<<P, 128, 0, stream>>>(bhist, bintot, nbin);
    k_gscan<<<1, 512, 0, stream>>>(bintot, gbase, rowptr, P, N, E);
    k_bin<<<nbin, 256, 0, stream>>>(esrc, edst, gbase, bhist, pk, P, E);
    k_sortrange<<<P, 512, 0, stream>>>(gbase, pk, ssrc, rowptr, dinv, N);
    k_gemm<<<(4 * N + 255) / 256, 256, 0, stream>>>(x, W, dinv, h2, N);
    k_nodeagg<<<ABLK, 256, 0, stream>>>(rowptr, ssrc, h2, dinv, b, a2, pstats, N);
    k_redstats<<<RBLK, 128, 0, stream>>>(pstats, pstats2);
    k_finstats<<<1, 1024, 0, stream>>>(pstats2, gamma, beta, scale, shift, N);
    k_bn2<<<1024, 256, 0, stream>>>(a2, scale, shift, out, N * DIM / 8);
}